// Round 1
// baseline (820.176 us; speedup 1.0000x reference)
//
#include <hip/hip_runtime.h>

#define HH 160
#define WW 160
#define C  64
#define PX 32      // pixels (w) per block
#define WXL 36     // halo width loaded (32 + 2*rmax)
#define WXP 37     // padded LDS row

// ---------------------------------------------------------------------------
// Pre-kernel: rearrange pw_w[2] from [576][64] to wR[b][kk][c'][c] so the main
// kernel's per-kk weight slice is a contiguous, coalesced [64][64] block.
// ---------------------------------------------------------------------------
__global__ __launch_bounds__(256) void prep_w_kernel(const float* __restrict__ pw0,
                                                     const float* __restrict__ pw1,
                                                     float* __restrict__ wR) {
    int idx = blockIdx.x * 256 + threadIdx.x;      // total 2*9*64*64 = 73728
    if (idx >= 2 * 9 * 64 * 64) return;
    int b  = idx / 36864;
    int r  = idx - b * 36864;
    int kk = r >> 12;          // / 4096
    int r2 = r & 4095;
    int cp = r2 >> 6;          // c' (input channel of the 1x1)
    int c  = r2 & 63;          // output channel group
    const float* src = b ? pw1 : pw0;
    wR[idx] = src[(c * 9 + kk) * 64 + cp];
}

// ---------------------------------------------------------------------------
// Fused kernel: dwconv+BN+ReLU -> per-pixel 1x1 GEMM (kk-sliced) -> unfold
// contraction -> sum branches -> final BN+ReLU.
// ---------------------------------------------------------------------------
__global__ __launch_bounds__(256) void fused_kernel(
    const float* __restrict__ y,   const float* __restrict__ x,
    const float* __restrict__ dw0, const float* __restrict__ g0,
    const float* __restrict__ bb0, const float* __restrict__ m0,
    const float* __restrict__ v0,  const float* __restrict__ pwb0,
    const float* __restrict__ dw1, const float* __restrict__ g1,
    const float* __restrict__ bb1, const float* __restrict__ m1,
    const float* __restrict__ v1,  const float* __restrict__ pwb1,
    const float* __restrict__ ng,  const float* __restrict__ nbb,
    const float* __restrict__ nm,  const float* __restrict__ nv,
    const float* __restrict__ wR,  float* __restrict__ out)
{
    __shared__ float buf[3][C][WXP];   // y halo tile, then reused for x halo tile
    __shared__ float t_lds[C][PX];     // [c'][px]
    __shared__ float w_lds[C][68];     // [c'][c], row 68 floats: 16B-aligned rows, 2-way max bank alias
    __shared__ float dwl[2 * 576];
    __shared__ float pwbl[2 * 576];
    __shared__ float sc[2][C], sh[2][C], nsc[C], nsh[C];

    const int tid = threadIdx.x;
    const int bid = blockIdx.x;
    const int n   = bid / (HH * 5);
    const int rem = bid - n * (HH * 5);
    const int h   = rem / 5;
    const int w0  = (rem - h * 5) * PX;

    // Per-channel BN folds (branch 0, branch 1, final norm)
    if (tid < C) {
        float s0 = g0[tid] * rsqrtf(v0[tid] + 1e-5f);
        sc[0][tid] = s0; sh[0][tid] = bb0[tid] - m0[tid] * s0;
        float s1 = g1[tid] * rsqrtf(v1[tid] + 1e-5f);
        sc[1][tid] = s1; sh[1][tid] = bb1[tid] - m1[tid] * s1;
        float sn = ng[tid] * rsqrtf(nv[tid] + 1e-5f);
        nsc[tid] = sn; nsh[tid] = nbb[tid] - nm[tid] * sn;
    }
    for (int e = tid; e < 576; e += 256) {
        dwl[e] = dw0[e];  dwl[576 + e] = dw1[e];
        pwbl[e] = pwb0[e]; pwbl[576 + e] = pwb1[e];
    }

    const int cg = tid & 15, pg = tid >> 4;
    const int c0 = cg * 4, px0 = pg * 2;   // thread owns 4 channels x 2 pixels
    float oacc[2][4];
    #pragma unroll
    for (int p = 0; p < 2; ++p)
        #pragma unroll
        for (int u = 0; u < 4; ++u) oacc[p][u] = 0.f;

    #pragma unroll
    for (int b = 0; b < 2; ++b) {
        const int r = b + 1;               // dilation: branch0 -> 1, branch1 -> 2
        // ---- stage y halo tile -------------------------------------------
        const float* ybase = y + n * (C * HH * WW);
        for (int e = tid; e < 3 * C * WXL; e += 256) {
            int i  = e / (C * WXL);
            int r1 = e - i * (C * WXL);
            int c  = r1 / WXL;
            int wl = r1 - c * WXL;
            int hg = h + (i - 1) * r;
            int wg = w0 - r + wl;
            float val = 0.f;
            if ((unsigned)hg < HH && (unsigned)wg < WW)
                val = ybase[(c * HH + hg) * WW + wg];
            buf[i][c][wl] = val;
        }
        __syncthreads();
        // ---- t = relu(bn(dwconv(y))) into LDS ----------------------------
        #pragma unroll 1
        for (int u = 0; u < 8; ++u) {
            int e  = tid + 256 * u;
            int cp = e >> 5;
            int px = e & 31;
            float acc = 0.f;
            #pragma unroll
            for (int i = 0; i < 3; ++i)
                #pragma unroll
                for (int j = 0; j < 3; ++j)
                    acc += buf[i][cp][px + j * r] * dwl[b * 576 + cp * 9 + i * 3 + j];
            float tv = acc * sc[b][cp] + sh[b][cp];
            t_lds[cp][px] = fmaxf(tv, 0.f);
        }
        __syncthreads();
        // ---- stage x halo tile (reuse buf) -------------------------------
        const float* xbase = x + n * (C * HH * WW);
        for (int e = tid; e < 3 * C * WXL; e += 256) {
            int i  = e / (C * WXL);
            int r1 = e - i * (C * WXL);
            int c  = r1 / WXL;
            int wl = r1 - c * WXL;
            int hg = h + (i - 1) * r;
            int wg = w0 - r + wl;
            float val = 0.f;
            if ((unsigned)hg < HH && (unsigned)wg < WW)
                val = xbase[(c * HH + hg) * WW + wg];
            buf[i][c][wl] = val;
        }
        __syncthreads();
        // ---- kk-sliced GEMM + unfold contraction -------------------------
        #pragma unroll 1
        for (int kk = 0; kk < 9; ++kk) {
            const float* wsrc = wR + ((b * 9 + kk) << 12);
            for (int e = tid; e < 4096; e += 256) {
                int cp = e >> 6, c = e & 63;
                w_lds[cp][c] = wsrc[e];
            }
            __syncthreads();

            float kern[2][4];
            #pragma unroll
            for (int u = 0; u < 4; ++u) {
                float bias = pwbl[b * 576 + (c0 + u) * 9 + kk];
                kern[0][u] = bias; kern[1][u] = bias;
            }
            #pragma unroll 8
            for (int cp = 0; cp < 64; ++cp) {
                const float2 a  = *(const float2*)&t_lds[cp][px0];
                const float4 wv = *(const float4*)&w_lds[cp][c0];
                kern[0][0] += a.x * wv.x; kern[1][0] += a.y * wv.x;
                kern[0][1] += a.x * wv.y; kern[1][1] += a.y * wv.y;
                kern[0][2] += a.x * wv.z; kern[1][2] += a.y * wv.z;
                kern[0][3] += a.x * wv.w; kern[1][3] += a.y * wv.w;
            }
            const int di = kk / 3, dj = kk - di * 3;
            const int xc = px0 + dj * r;
            #pragma unroll
            for (int u = 0; u < 4; ++u) {
                float xv0 = buf[di][c0 + u][xc];
                float xv1 = buf[di][c0 + u][xc + 1];
                oacc[0][u] += kern[0][u] * xv0;
                oacc[1][u] += kern[1][u] * xv1;
            }
            __syncthreads();   // before next kk overwrites w_lds / next branch overwrites buf
        }
    }
    // ---- final BN + ReLU, store ------------------------------------------
    #pragma unroll
    for (int u = 0; u < 4; ++u) {
        int c = c0 + u;
        float o0 = fmaxf(oacc[0][u] * nsc[c] + nsh[c], 0.f);
        float o1 = fmaxf(oacc[1][u] * nsc[c] + nsh[c], 0.f);
        float2 o2 = make_float2(o0, o1);
        *(float2*)&out[((n * C + c) * HH + h) * WW + w0 + px0] = o2;
    }
}

extern "C" void kernel_launch(void* const* d_in, const int* in_sizes, int n_in,
                              void* d_out, int out_size, void* d_ws, size_t ws_size,
                              hipStream_t stream) {
    const float* y    = (const float*)d_in[0];
    const float* x    = (const float*)d_in[1];
    const float* dw0  = (const float*)d_in[2];
    const float* g0   = (const float*)d_in[3];
    const float* b0   = (const float*)d_in[4];
    const float* m0   = (const float*)d_in[5];
    const float* v0   = (const float*)d_in[6];
    const float* pw0  = (const float*)d_in[7];
    const float* pwb0 = (const float*)d_in[8];
    const float* dw1  = (const float*)d_in[9];
    const float* g1   = (const float*)d_in[10];
    const float* b1   = (const float*)d_in[11];
    const float* m1   = (const float*)d_in[12];
    const float* v1   = (const float*)d_in[13];
    const float* pw1  = (const float*)d_in[14];
    const float* pwb1 = (const float*)d_in[15];
    const float* ng   = (const float*)d_in[16];
    const float* nb   = (const float*)d_in[17];
    const float* nm   = (const float*)d_in[18];
    const float* nv   = (const float*)d_in[19];

    float* wR = (float*)d_ws;   // 2*9*64*64 floats = 294912 B

    prep_w_kernel<<<288, 256, 0, stream>>>(pw0, pw1, wR);
    fused_kernel<<<3200, 256, 0, stream>>>(y, x,
                                           dw0, g0, b0, m0, v0, pwb0,
                                           dw1, g1, b1, m1, v1, pwb1,
                                           ng, nb, nm, nv, wR, (float*)d_out);
}

// Round 2
// 487.267 us; speedup vs baseline: 1.6832x; 1.6832x over previous
//
#include <hip/hip_runtime.h>

#define HH 160
#define WW 160

typedef __attribute__((ext_vector_type(8))) short bf16x8;
typedef __attribute__((ext_vector_type(4))) float f32x4;

__device__ __forceinline__ unsigned short f32_to_bf16_rne(float f) {
    unsigned u = __float_as_uint(f);
    unsigned r = (u + 0x7FFFu + ((u >> 16) & 1u)) >> 16;
    return (unsigned short)r;
}
__device__ __forceinline__ float bf16_to_f32(unsigned short h) {
    return __uint_as_float(((unsigned)h) << 16);
}

// ---------------------------------------------------------------------------
// Prep: pack pw_w[2] into MFMA B-fragment layout, bf16 hi/lo split.
// wF layout: frag = (((b*9+kk)*4 + ct)*2 + kh)*2 + comp ; per frag 64 lanes x 8 u16.
// Element (lane,j): B[k=kh*32+(lane>>4)*8+j][n=ct*16+(lane&15)] of W[cp][c]=pw[(c*9+kk)*64+cp]
// Total 288 frags * 1024B = 294912 B.
// ---------------------------------------------------------------------------
__global__ __launch_bounds__(256) void prep_w_kernel(const float* __restrict__ pw0,
                                                     const float* __restrict__ pw1,
                                                     unsigned short* __restrict__ wF) {
    int idx = blockIdx.x * 256 + threadIdx.x;   // 288*64 = 18432
    if (idx >= 18432) return;
    int lane = idx & 63;
    int frag = idx >> 6;
    int comp = frag & 1;
    int kh   = (frag >> 1) & 1;
    int ct   = (frag >> 2) & 3;
    int t    = frag >> 4;             // b*9+kk
    int bb   = t / 9;
    int kk   = t - bb * 9;
    const float* pw = bb ? pw1 : pw0;
    int c = ct * 16 + (lane & 15);
    unsigned short o8[8];
    #pragma unroll
    for (int j = 0; j < 8; ++j) {
        int cp = kh * 32 + (lane >> 4) * 8 + j;
        float v = pw[(c * 9 + kk) * 64 + cp];
        unsigned short hb = f32_to_bf16_rne(v);
        if (comp == 0) o8[j] = hb;
        else {
            float lo = v - bf16_to_f32(hb);
            o8[j] = f32_to_bf16_rne(lo);
        }
    }
    bf16x8 pack;
    #pragma unroll
    for (int j = 0; j < 8; ++j) pack[j] = (short)o8[j];
    *(bf16x8*)&wF[frag * 512 + lane * 8] = pack;
}

// ---------------------------------------------------------------------------
// Fused main kernel. Tile = 2 h-rows x 32 w = 64 px, all 64 channels.
// 4 waves; wave wid owns output channels [wid*16, wid*16+16) for all 64 px.
// GEMM kern[px][c,kk] = t[px][cp] @ W[cp][(c,kk)] via mfma_f32_16x16x32_bf16,
// bf16x3 split (hi*hi + hi*lo + lo*hi). Contract with x per kk immediately.
// ---------------------------------------------------------------------------
__global__ __launch_bounds__(256, 2) void fused_kernel(
    const float* __restrict__ y,   const float* __restrict__ x,
    const float* __restrict__ dw0, const float* __restrict__ g0,
    const float* __restrict__ bb0, const float* __restrict__ m0,
    const float* __restrict__ v0,  const float* __restrict__ pwb0,
    const float* __restrict__ dw1, const float* __restrict__ g1,
    const float* __restrict__ bb1, const float* __restrict__ m1,
    const float* __restrict__ v1,  const float* __restrict__ pwb1,
    const float* __restrict__ ng,  const float* __restrict__ nbb,
    const float* __restrict__ nm,  const float* __restrict__ nv,
    const unsigned short* __restrict__ wF, float* __restrict__ out)
{
    __shared__ float xbufF[2 * 2 * 64 * 37];           // 37888 B, [dbuf][row][c][37]
    __shared__ unsigned short t_hi[64 * 64];           // 8192 B  [px][cp], chunk-XOR swizzle
    __shared__ unsigned short t_lo[64 * 64];           // 8192 B
    __shared__ float dwl[2 * 576];                     // 4608 B
    __shared__ float scb[2 * 64], shb[2 * 64], nscl[64], nshl[64];  // 1536 B

    const int tid  = threadIdx.x;
    const int lane = tid & 63;
    const int wid  = tid >> 6;          // wave id = ct (c-group)
    const int pg   = lane >> 4;
    const int cc   = wid * 16 + (lane & 15);   // this lane's output channel

    const int bid = blockIdx.x;         // 4 * 80 * 5 = 1600
    const int n   = bid / 400;
    const int rem = bid - n * 400;
    const int ht  = rem / 5;
    const int wt  = rem - ht * 5;
    const int h   = ht * 2;
    const int w0  = wt * 32;

    const float* ybase = y + n * (64 * HH * WW);
    const float* xbase = x + n * (64 * HH * WW);

    // ---- one-time staging: dw weights + BN folds -------------------------
    for (int e = tid; e < 576; e += 256) { dwl[e] = dw0[e]; dwl[576 + e] = dw1[e]; }
    if (tid < 64) {
        float s0 = g0[tid] * rsqrtf(v0[tid] + 1e-5f);
        scb[tid] = s0;      shb[tid] = bb0[tid] - m0[tid] * s0;
        float s1 = g1[tid] * rsqrtf(v1[tid] + 1e-5f);
        scb[64 + tid] = s1; shb[64 + tid] = bb1[tid] - m1[tid] * s1;
        float sn = ng[tid] * rsqrtf(nv[tid] + 1e-5f);
        nscl[tid] = sn;     nshl[tid] = nbb[tid] - nm[tid] * sn;
    }
    __syncthreads();

    float outacc[4][4];
    #pragma unroll
    for (int mt = 0; mt < 4; ++mt)
        #pragma unroll
        for (int rr = 0; rr < 4; ++rr) outacc[mt][rr] = 0.f;

    #pragma unroll
    for (int b = 0; b < 2; ++b) {
        const int r = b + 1;
        const float* pwbg = b ? pwb1 : pwb0;

        // ---- depthwise conv + BN + ReLU -> t (bf16 hi/lo, swizzled) ------
        {
            const int px = tid & 63;
            const int rl = px >> 5, wl = px & 31;
            #pragma unroll
            for (int it = 0; it < 2; ++it) {
                int chunk = (tid >> 6) + it * 4;    // 0..7
                int cp0 = chunk * 8;
                bf16x8 h8, l8;
                #pragma unroll
                for (int jc = 0; jc < 8; ++jc) {
                    int cp = cp0 + jc;
                    float a = 0.f;
                    #pragma unroll
                    for (int i = 0; i < 3; ++i) {
                        int hr = h + rl + (i - 1) * r;
                        const float* yr = ybase + (cp * HH + hr) * WW;
                        bool hok = (unsigned)hr < (unsigned)HH;
                        #pragma unroll
                        for (int j = 0; j < 3; ++j) {
                            int wc = w0 + wl + (j - 1) * r;
                            float yv = (hok && (unsigned)wc < (unsigned)WW) ? yr[wc] : 0.f;
                            a += yv * dwl[b * 576 + cp * 9 + i * 3 + j];
                        }
                    }
                    float tv = fmaxf(a * scb[b * 64 + cp] + shb[b * 64 + cp], 0.f);
                    unsigned short hb = f32_to_bf16_rne(tv);
                    float lo = tv - bf16_to_f32(hb);
                    h8[jc] = (short)hb;
                    l8[jc] = (short)f32_to_bf16_rne(lo);
                }
                int phys = chunk ^ ((px >> 1) & 7);
                *(bf16x8*)&t_hi[px * 64 + phys * 8] = h8;
                *(bf16x8*)&t_lo[px * 64 + phys * 8] = l8;
            }
        }
        __syncthreads();   // t ready; xbuf free (prev branch fully consumed)

        // ---- load A fragments (held in regs for the whole branch) --------
        bf16x8 afr[4][2][2];
        #pragma unroll
        for (int mt = 0; mt < 4; ++mt) {
            int pxl = mt * 16 + (lane & 15);
            #pragma unroll
            for (int kh = 0; kh < 2; ++kh) {
                int chunk = kh * 4 + (lane >> 4);
                int phys  = chunk ^ ((pxl >> 1) & 7);
                int off   = pxl * 64 + phys * 8;
                afr[mt][kh][0] = *(const bf16x8*)&t_hi[off];
                afr[mt][kh][1] = *(const bf16x8*)&t_lo[off];
            }
        }

        // ---- bias preload ------------------------------------------------
        float biasr[9];
        #pragma unroll
        for (int kk = 0; kk < 9; ++kk) biasr[kk] = pwbg[cc * 9 + kk];

        // ---- stage x rows for di=0 into xbuf[0] --------------------------
        #pragma unroll 1
        for (int e = tid; e < 4608; e += 256) {
            int rI = e / 2304; int r2 = e - rI * 2304;
            int c = r2 / 36;   int col = r2 - c * 36;
            int hr = h + rI + (0 - 1) * r;
            int wc = w0 - 2 + col;
            float v = 0.f;
            if ((unsigned)hr < (unsigned)HH && (unsigned)wc < (unsigned)WW)
                v = xbase[(c * HH + hr) * WW + wc];
            xbufF[((0 * 2 + rI) * 64 + c) * 37 + col] = v;
        }
        __syncthreads();

        #pragma unroll
        for (int di = 0; di < 3; ++di) {
            const int cur = di & 1;
            // prefetch-stage next di into the other buffer
            if (di < 2) {
                const int tb = (di + 1) & 1;
                #pragma unroll 1
                for (int e = tid; e < 4608; e += 256) {
                    int rI = e / 2304; int r2 = e - rI * 2304;
                    int c = r2 / 36;   int col = r2 - c * 36;
                    int hr = h + rI + (di + 1 - 1) * r;
                    int wc = w0 - 2 + col;
                    float v = 0.f;
                    if ((unsigned)hr < (unsigned)HH && (unsigned)wc < (unsigned)WW)
                        v = xbase[(c * HH + hr) * WW + wc];
                    xbufF[((tb * 2 + rI) * 64 + c) * 37 + col] = v;
                }
            }
            #pragma unroll
            for (int dj = 0; dj < 3; ++dj) {
                const int kk = di * 3 + dj;
                // B fragments: global (L2-resident), fragment-packed
                const unsigned short* wfb = wF + (((b * 9 + kk) * 4 + wid) * 4) * 512;
                bf16x8 bfr[2][2];
                #pragma unroll
                for (int kh = 0; kh < 2; ++kh)
                    #pragma unroll
                    for (int cm = 0; cm < 2; ++cm)
                        bfr[kh][cm] = *(const bf16x8*)&wfb[(kh * 2 + cm) * 512 + lane * 8];

                float bv = biasr[kk];
                f32x4 kern[4];
                #pragma unroll
                for (int mt = 0; mt < 4; ++mt) kern[mt] = (f32x4){bv, bv, bv, bv};

                // bf16x3: hi*hi, hi*lo, lo*hi
                #pragma unroll
                for (int p = 0; p < 3; ++p) {
                    const int ac = (p == 2) ? 1 : 0;
                    const int bc = (p == 1) ? 1 : 0;
                    #pragma unroll
                    for (int kh = 0; kh < 2; ++kh)
                        #pragma unroll
                        for (int mt = 0; mt < 4; ++mt)
                            kern[mt] = __builtin_amdgcn_mfma_f32_16x16x32_bf16(
                                afr[mt][kh][ac], bfr[kh][bc], kern[mt], 0, 0, 0);
                }

                // contract with x tile
                #pragma unroll
                for (int mt = 0; mt < 4; ++mt) {
                    const float* xb = &xbufF[((cur * 2 + (mt >> 1)) * 64 + cc) * 37
                                             + (mt & 1) * 16 + pg * 4 + 2 + (dj - 1) * r];
                    #pragma unroll
                    for (int rr = 0; rr < 4; ++rr)
                        outacc[mt][rr] += kern[mt][rr] * xb[rr];
                }
            }
            __syncthreads();   // di buffer consumed; next-staged buffer ready
        }
    }

    // ---- epilogue: final BN+ReLU, transpose via LDS, coalesced store -----
    float* obuf = xbufF;   // reuse (16640 B needed)
    {
        float sn = nscl[cc], sh = nshl[cc];
        #pragma unroll
        for (int mt = 0; mt < 4; ++mt)
            #pragma unroll
            for (int rr = 0; rr < 4; ++rr) {
                int pxp = mt * 16 + pg * 4 + rr;
                obuf[cc * 65 + pxp] = fmaxf(outacc[mt][rr] * sn + sh, 0.f);
            }
    }
    __syncthreads();
    {
        int c2 = tid >> 2;
        int px0 = (tid & 3) * 16;
        int rl2 = px0 >> 5, wl2 = px0 & 31;
        float* op = out + ((n * 64 + c2) * HH + (h + rl2)) * WW + w0 + wl2;
        #pragma unroll
        for (int q = 0; q < 4; ++q) {
            float4 v4 = make_float4(obuf[c2 * 65 + px0 + q * 4 + 0],
                                    obuf[c2 * 65 + px0 + q * 4 + 1],
                                    obuf[c2 * 65 + px0 + q * 4 + 2],
                                    obuf[c2 * 65 + px0 + q * 4 + 3]);
            *(float4*)(op + q * 4) = v4;
        }
    }
}

extern "C" void kernel_launch(void* const* d_in, const int* in_sizes, int n_in,
                              void* d_out, int out_size, void* d_ws, size_t ws_size,
                              hipStream_t stream) {
    const float* y    = (const float*)d_in[0];
    const float* x    = (const float*)d_in[1];
    const float* dw0  = (const float*)d_in[2];
    const float* g0   = (const float*)d_in[3];
    const float* b0   = (const float*)d_in[4];
    const float* m0   = (const float*)d_in[5];
    const float* v0   = (const float*)d_in[6];
    const float* pw0  = (const float*)d_in[7];
    const float* pwb0 = (const float*)d_in[8];
    const float* dw1  = (const float*)d_in[9];
    const float* g1   = (const float*)d_in[10];
    const float* b1   = (const float*)d_in[11];
    const float* m1   = (const float*)d_in[12];
    const float* v1   = (const float*)d_in[13];
    const float* pw1  = (const float*)d_in[14];
    const float* pwb1 = (const float*)d_in[15];
    const float* ng   = (const float*)d_in[16];
    const float* nb   = (const float*)d_in[17];
    const float* nm   = (const float*)d_in[18];
    const float* nv   = (const float*)d_in[19];

    unsigned short* wF = (unsigned short*)d_ws;   // 294912 B

    prep_w_kernel<<<72, 256, 0, stream>>>(pw0, pw1, wF);
    fused_kernel<<<1600, 256, 0, stream>>>(y, x,
                                           dw0, g0, b0, m0, v0, pwb0,
                                           dw1, g1, b1, m1, v1, pwb1,
                                           ng, nb, nm, nv, wF, (float*)d_out);
}